// Round 7
// baseline (1183.035 us; speedup 1.0000x reference)
//
#include <hip/hip_runtime.h>

#define KTOT 65536
#define QN 16
#define DN 64
#define BN 8
#define TILE 256

// smem layout (floats) — 9216 floats = 36,864 B
#define QS_OFF 0                    // Q scaled: [16][64]                 = 1024 floats
#define R0_OFF 1024                 // K quarter region 0: [256][16]      = 4096
#define R1_OFF 5120                 // K quarter region 1: [256][16]      = 4096
                                    // R1 doubles as A: per-wave [16][64] slices (wave-private)
#define SMEM_FLOATS 9216

// async global->LDS, 16B per lane; dest = lane0's pointer + lane*16 (rounds 3-6 verified)
__device__ __forceinline__ void gload_lds16(const float* g, float* l)
{
    __builtin_amdgcn_global_load_lds(
        (const __attribute__((address_space(1))) void*)g,
        (__attribute__((address_space(3))) void*)l, 16, 0, 0);
}

// Counted wait: "memory" clobber pins every memory op on its side of the wait, so the
// vmcnt count is robust (wanted loads always have >=N younger ops => can't under-wait;
// vmcnt retires strictly in order). sched_barrier stops reg-only ops hoisting (rule #18).
#define WAIT_VM(N)  do { asm volatile("s_waitcnt vmcnt(" #N ")" ::: "memory");      \
                         __builtin_amdgcn_sched_barrier(0); } while (0)
// Ensure this wave's ds_reads have retired (data in VGPRs) before gload_lds overwrites
#define LGKM0()     asm volatile("s_waitcnt lgkmcnt(0)" ::: "memory")

// WAVE-PRIVATE staging: wave wv stages ITS OWN rows 64wv..64wv+63 (quarter = 16 float
// cols, qo4 = quarter*4 in float4 units). Dest float4 slot = 256wv + 64j + lane ==
// row-major [256][4] slot for row 64wv+16j+(lane>>2), col lane&3 (wave-uniform+lane).
// Source pre-swizzled: global col = (lane&3) ^ ((row>>1)&3); read side applies same XOR.
#define STAGE_WV(RX, kb4, qo4)                                                      \
    {                                                                               \
        _Pragma("unroll")                                                           \
        for (int j = 0; j < 4; ++j) {                                               \
            const int r_ = (wv << 6) + (j << 4) + (lane >> 2);                      \
            const int p_ = (lane & 3) ^ ((r_ >> 1) & 3);                            \
            gload_lds16((const float*)((kb4) + r_ * 16 + (qo4) + p_),               \
                        (float*)(((float4*)&smem[RX]) + ((wv << 8) + (j << 6) + lane))); \
        }                                                                           \
    }

// dot quarter qt from region RX: thread owns row tid; Q broadcast from LDS
#define DOT_Q(qt, RX)                                                               \
    {                                                                               \
        _Pragma("unroll")                                                           \
        for (int cc = 0; cc < 4; ++cc) {                                            \
            const float4 kv = ((const float4*)&smem[RX])[tid * 4 + (cc ^ fr)];      \
            _Pragma("unroll")                                                       \
            for (int q = 0; q < QN; ++q) {                                          \
                const float4 qv = *reinterpret_cast<const float4*>(                 \
                    &smem[QS_OFF + q * DN + (qt) * 16 + cc * 4]);                   \
                s[q] = fmaf(kv.x, qv.x, s[q]);                                      \
                s[q] = fmaf(kv.y, qv.y, s[q]);                                      \
                s[q] = fmaf(kv.z, qv.z, s[q]);                                      \
                s[q] = fmaf(kv.w, qv.w, s[q]);                                      \
            }                                                                       \
        }                                                                           \
    }

#define VLOAD16(dst, base_r)                                                        \
    {                                                                               \
        _Pragma("unroll")                                                           \
        for (int i = 0; i < 16; ++i) dst[i] = vptr[(size_t)((base_r) + i) * DN];    \
    }

// PV over 16 k's starting at k0 using V batch vreg (A broadcast from own R1 slice)
#define PV16(vreg, k0)                                                              \
    {                                                                               \
        _Pragma("unroll")                                                           \
        for (int kq = 0; kq < 4; ++kq) {                                            \
            _Pragma("unroll")                                                       \
            for (int q = 0; q < QN; ++q) {                                          \
                const float4 av = *reinterpret_cast<const float4*>(                 \
                    &smem[AW + q * 64 + (k0) + kq * 4]);                            \
                U[q] = fmaf(av.x, vreg[kq * 4 + 0], U[q]);                          \
                U[q] = fmaf(av.y, vreg[kq * 4 + 1], U[q]);                          \
                U[q] = fmaf(av.z, vreg[kq * 4 + 2], U[q]);                          \
                U[q] = fmaf(av.w, vreg[kq * 4 + 3], U[q]);                          \
            }                                                                       \
        }                                                                           \
    }

// ---------------- Fused: QK^T + softmax(Q) + attn write + PV partials + norm partials --------
// ZERO barriers in the main loop: K staging is wave-private (K rows have no cross-thread
// reuse), A is wave-private, Q is read-only after one prologue barrier. All waits are
// wave-local counted vmcnt -> waves free-run and phase-shift instead of lockstep-draining.
__global__ __launch_bounds__(256, 3) void fused_attn(
    const float* __restrict__ query, const float* __restrict__ key,
    const float* __restrict__ value, float* __restrict__ attn,
    float* __restrict__ normp, float* __restrict__ upart,
    int NCH, int ntiles)
{
    __shared__ float smem[SMEM_FLOATS];
    const int b    = blockIdx.y;
    const int c    = blockIdx.x;
    const int tid  = threadIdx.x;
    const int wv   = tid >> 6;
    const int lane = tid & 63;
    const int chunk = ntiles * TILE;
    const int fr   = (tid >> 1) & 3;
    const int AW   = R1_OFF + wv * (QN * 64);   // A: own slice of R1

    // Q -> LDS (scaled), ONE barrier, then prologue K stages (after barrier: not drained)
    {
        float4 qv = reinterpret_cast<const float4*>(query + (size_t)b * QN * DN)[tid];
        qv.x *= 0.125f; qv.y *= 0.125f; qv.z *= 0.125f; qv.w *= 0.125f;
        reinterpret_cast<float4*>(&smem[QS_OFF])[tid] = qv;
    }
    __syncthreads();

    {
        const float4* kb4 = reinterpret_cast<const float4*>(
            key + ((size_t)b * KTOT + c * chunk) * DN);
        STAGE_WV(R0_OFF, kb4, 0);   // tile0 quarter0
        STAGE_WV(R1_OFF, kb4, 4);   // tile0 quarter1
    }

    float U[QN], nacc[QN];
    #pragma unroll
    for (int q = 0; q < QN; ++q) { U[q] = 0.f; nacc[q] = 0.f; }

    for (int t = 0; t < ntiles; ++t) {
        const int krow0 = c * chunk + t * TILE;
        const float4* kb4  = reinterpret_cast<const float4*>(
            key + ((size_t)b * KTOT + krow0) * DN);
        const float4* kb4n = kb4 + TILE * 16;                         // next tile
        const float*  vptr = value + ((size_t)b * KTOT + krow0 + wv * 64) * DN + lane;

        float s[QN];
        #pragma unroll
        for (int q = 0; q < QN; ++q) s[q] = 0.f;

        // q0: outstanding {Kq0,Kq1}(8) [+old attn stores] -> wait<=4 drains Kq0
        WAIT_VM(4);
        DOT_Q(0, R0_OFF);
        LGKM0(); STAGE_WV(R0_OFF, kb4, 8);                            // Kq2 -> R0

        // q1: outstanding {Kq1,Kq2}(8) -> drains Kq1
        WAIT_VM(4);
        DOT_Q(1, R1_OFF);
        LGKM0(); STAGE_WV(R1_OFF, kb4, 12);                           // Kq3 -> R1

        // q2: outstanding {Kq2,Kq3}(8) -> drains Kq2; V batch0 rides through dot
        WAIT_VM(4);
        float v0[16]; VLOAD16(v0, 0);
        DOT_Q(2, R0_OFF);

        // q3: outstanding {Kq3(4 oldest), v0(16)} = 20 -> wait<=16 drains Kq3 only
        WAIT_VM(16);
        float v1[16]; VLOAD16(v1, 16);
        DOT_Q(3, R1_OFF);

        // softmax over the 16 queries (thread-local, k = krow0 + tid)
        float m = s[0];
        #pragma unroll
        for (int q = 1; q < QN; ++q) m = fmaxf(m, s[q]);
        float sum = 0.f;
        #pragma unroll
        for (int q = 0; q < QN; ++q) { s[q] = __expf(s[q] - m); sum += s[q]; }
        const float inv = 1.0f / sum;
        {
            float* ab = attn + (size_t)b * QN * KTOT + krow0 + tid;
            #pragma unroll
            for (int q = 0; q < QN; ++q) {
                const float a = s[q] * inv;
                __builtin_nontemporal_store(a, ab + (size_t)q * KTOT);
                smem[AW + q * 64 + lane] = a;        // own slice; DS in-order after dot q3
                nacc[q] += a;
            }
        }

        // PV: 4 sub-blocks of 16 k; V batch i+2 and next-tile K stages ride through
        float v2[16]; VLOAD16(v2, 32);
        if (t + 1 < ntiles) { LGKM0(); STAGE_WV(R0_OFF, kb4n, 0); }   // Kq0' -> R0
        PV16(v0, 0);
        float v3[16]; VLOAD16(v3, 48);
        PV16(v1, 16);
        PV16(v2, 32);
        PV16(v3, 48);
        if (t + 1 < ntiles) { LGKM0(); STAGE_WV(R1_OFF, kb4n, 4); }   // Kq1' -> R1
    }

    // ---- block reductions: U across 4 waves (R0 region), nacc (R1 region) ----
    __syncthreads();
    #pragma unroll
    for (int q = 0; q < QN; ++q)
        smem[R0_OFF + (wv * QN + q) * DN + lane] = U[q];
    #pragma unroll
    for (int q = 0; q < QN; ++q) {
        #pragma unroll
        for (int off = 1; off < 64; off <<= 1)
            nacc[q] += __shfl_xor(nacc[q], off, 64);
    }
    if (lane == 0) {
        #pragma unroll
        for (int q = 0; q < QN; ++q) smem[R1_OFF + wv * QN + q] = nacc[q];
    }
    __syncthreads();

    {
        const int q = tid >> 4, d0 = (tid & 15) * 4;
        const float4 r0 = *reinterpret_cast<const float4*>(&smem[R0_OFF + (0 * QN + q) * DN + d0]);
        const float4 r1 = *reinterpret_cast<const float4*>(&smem[R0_OFF + (1 * QN + q) * DN + d0]);
        const float4 r2 = *reinterpret_cast<const float4*>(&smem[R0_OFF + (2 * QN + q) * DN + d0]);
        const float4 r3 = *reinterpret_cast<const float4*>(&smem[R0_OFF + (3 * QN + q) * DN + d0]);
        float4 rs;
        rs.x = r0.x + r1.x + r2.x + r3.x;
        rs.y = r0.y + r1.y + r2.y + r3.y;
        rs.z = r0.z + r1.z + r2.z + r3.z;
        rs.w = r0.w + r1.w + r2.w + r3.w;
        *reinterpret_cast<float4*>(
            &upart[(((size_t)b * NCH + c) * QN + q) * DN + d0]) = rs;
        if (tid < QN)
            normp[((size_t)b * NCH + c) * QN + tid] =
                smem[R1_OFF + tid] + smem[R1_OFF + QN + tid] +
                smem[R1_OFF + 2 * QN + tid] + smem[R1_OFF + 3 * QN + tid];
    }
}

// ---------------- Finalize: out[b][q][d] = sum_c U / (sum_c norm + eps); grid (8,16) --------
__global__ __launch_bounds__(256) void k3_fin(
    const float* __restrict__ upart, const float* __restrict__ normp,
    float* __restrict__ out, int NCH)
{
    const int b = blockIdx.x, q = blockIdx.y;
    const int tid = threadIdx.x;
    const int wv = tid >> 6, lane = tid & 63;

    float nv = 0.f;
    for (int c = tid; c < NCH; c += 256)
        nv += normp[((size_t)b * NCH + c) * QN + q];
    #pragma unroll
    for (int off = 1; off < 64; off <<= 1) nv += __shfl_xor(nv, off, 64);
    __shared__ float nred[4];
    if (lane == 0) nred[wv] = nv;

    float acc = 0.f;
    for (int c = wv; c < NCH; c += 4)
        acc += upart[(((size_t)b * NCH + c) * QN + q) * DN + lane];
    __shared__ float ured[4][DN];
    ured[wv][lane] = acc;
    __syncthreads();

    if (tid < DN) {
        const float n   = nred[0] + nred[1] + nred[2] + nred[3];
        const float inv = 1.0f / (n + 1e-8f);
        const float u   = ured[0][tid] + ured[1][tid] + ured[2][tid] + ured[3][tid];
        out[((size_t)b * QN + q) * DN + tid] = u * inv;
    }
}

extern "C" void kernel_launch(void* const* d_in, const int* in_sizes, int n_in,
                              void* d_out, int out_size, void* d_ws, size_t ws_size,
                              hipStream_t stream)
{
    const float* query = (const float*)d_in[0];
    const float* key   = (const float*)d_in[1];
    const float* value = (const float*)d_in[2];

    float* out  = (float*)d_out;                          // [8,16,64]
    float* attn = (float*)d_out + (size_t)BN * QN * DN;   // [8,1,16,65536]

    int NCH = 128;                                        // 1024 blocks
    while (NCH > 8 && (size_t)BN * NCH * QN * (DN + 1) * 4 > ws_size) NCH >>= 1;
    const int ntiles = (KTOT / NCH) / TILE;

    float* normp = (float*)d_ws;                          // [8][NCH][16]
    float* upart = (float*)d_ws + (size_t)BN * NCH * QN;  // [8][NCH][16][64]

    fused_attn<<<dim3(NCH, BN), 256, 0, stream>>>(query, key, value, attn,
                                                  normp, upart, NCH, ntiles);
    k3_fin   <<<dim3(BN, QN), 256, 0, stream>>>(upart, normp, out, NCH);
}

// Round 8
// 150.947 us; speedup vs baseline: 7.8374x; 7.8374x over previous
//
#include <hip/hip_runtime.h>

#define KTOT 65536
#define QN 16
#define DN 64
#define BN 8
#define TILE 256

// smem layout (floats) — 8192 floats = 32,768 B (Q region removed: Q now via scalar loads)
#define R0_OFF 0                    // K quarter region 0: [256][16]      = 4096
#define R1_OFF 4096                 // K quarter region 1: [256][16]      = 4096
                                    // R1 doubles as A: per-wave [16][64] slices (wave-private)
#define SMEM_FLOATS 8192

// async global->LDS, 16B per lane; LDS dest linear (wave-uniform base + lane*16)
__device__ __forceinline__ void gload_lds16(const float* g, float* l)
{
    __builtin_amdgcn_global_load_lds(
        (const __attribute__((address_space(1))) void*)g,
        (__attribute__((address_space(3))) void*)l, 16, 0, 0);
}

// Stage one K quarter (16KB: 256 rows x 4 float4) into region RX.
// Source is PRE-SWIZZLED so LDS slot (r,p) holds global col (p ^ ((r>>1)&3));
// read side applies the same XOR. (verified rounds 3-6)
#define STAGE_QUARTER(RX, kb4, qo4)                                          \
    {                                                                        \
        _Pragma("unroll")                                                    \
        for (int j = 0; j < 4; ++j) {                                        \
            const int s_ = j * 256 + tid;                                    \
            const int r_ = s_ >> 2, p_ = s_ & 3;                             \
            const int f_ = (r_ >> 1) & 3;                                    \
            gload_lds16((const float*)((kb4) + r_ * 16 + (qo4) + (p_ ^ f_)), \
                        (float*)(((float4*)&smem[RX]) + s_));                \
        }                                                                    \
    }

// ---------------- Fused: QK^T + softmax(Q) + attn write + PV partials + norm partials --------
// Round-8 change vs round 6 (which measured 139us warm, 84 VGPR, no spills): Q is read from
// GLOBAL with wave-uniform addresses -> compiler emits s_load (scalar cache, read-only data,
// coherence-safe). This removes 256 ds_read_b128 broadcasts per wave-tile (~47% of all DS
// traffic) from the per-CU LDS pipe — the resource every round-3..6 variant saturated
// identically. Scale 1/8 applied once post-dot (power of 2 -> bitwise-identical).
__global__ __launch_bounds__(256, 3) void fused_attn(
    const float* __restrict__ query, const float* __restrict__ key,
    const float* __restrict__ value, float* __restrict__ attn,
    float* __restrict__ normp, float* __restrict__ upart,
    int NCH, int ntiles)
{
    __shared__ float smem[SMEM_FLOATS];
    const int b    = blockIdx.y;
    const int c    = blockIdx.x;
    const int tid  = threadIdx.x;
    const int wv   = tid >> 6;
    const int lane = tid & 63;
    const int chunk = ntiles * TILE;

    // wave-uniform Q base (float4 rows of 16): compiler scalarizes loads off this
    const float4* qg = reinterpret_cast<const float4*>(query + (size_t)b * QN * DN);

    // prologue: issue tile0/quarter0 ASAP (async, no VGPR cost)
    {
        const float4* kb4 = reinterpret_cast<const float4*>(
            key + ((size_t)b * KTOT + c * chunk) * DN);
        STAGE_QUARTER(R0_OFF, kb4, 0);
    }

    float U[QN], nacc[QN];
    #pragma unroll
    for (int q = 0; q < QN; ++q) { U[q] = 0.f; nacc[q] = 0.f; }

    const int fr = (tid >> 1) & 3;          // read-side swizzle for row tid

    for (int t = 0; t < ntiles; ++t) {
        const int krow0 = c * chunk + t * TILE;
        const float4* kb4 = reinterpret_cast<const float4*>(
            key + ((size_t)b * KTOT + krow0) * DN);

        float s[QN];
        #pragma unroll
        for (int q = 0; q < QN; ++q) s[q] = 0.f;

        // ---- 4 pipelined dot quarters; barrier at top of qt drains the in-flight
        //      quarter qt; quarter qt+1 is issued immediately and rides through the dot ----
        #pragma unroll
        for (int qt = 0; qt < 4; ++qt) {
            __syncthreads();                              // quarter qt visible in R[qt&1]
            if (qt < 3) {
                if (qt & 1) { STAGE_QUARTER(R0_OFF, kb4, (qt + 1) * 4); }
                else        { STAGE_QUARTER(R1_OFF, kb4, (qt + 1) * 4); }
            }
            const int RX = (qt & 1) ? R1_OFF : R0_OFF;
            #pragma unroll
            for (int cc = 0; cc < 4; ++cc) {
                const float4 kv = ((const float4*)&smem[RX])[tid * 4 + (cc ^ fr)];
                #pragma unroll
                for (int q = 0; q < QN; ++q) {
                    const float4 qv = qg[q * 16 + qt * 4 + cc];   // uniform -> s_load
                    s[q] = fmaf(kv.x, qv.x, s[q]);
                    s[q] = fmaf(kv.y, qv.y, s[q]);
                    s[q] = fmaf(kv.z, qv.z, s[q]);
                    s[q] = fmaf(kv.w, qv.w, s[q]);
                }
            }
        }

        // ---------- NO BARRIER from here to the end of PV: wave-private dataflow ----------

        // ---- scale (exact pow2) + softmax over the 16 queries (thread-local) ----
        #pragma unroll
        for (int q = 0; q < QN; ++q) s[q] *= 0.125f;
        float m = s[0];
        #pragma unroll
        for (int q = 1; q < QN; ++q) m = fmaxf(m, s[q]);
        float sum = 0.f;
        #pragma unroll
        for (int q = 0; q < QN; ++q) { s[q] = __expf(s[q] - m); sum += s[q]; }
        const float inv = 1.0f / sum;

        // A lives in this wave's private slice of R1 (rows wv*64..+63 == the slice
        // this wave alone read in qt3); layout [16 q][64 k-local]
        const int AW = R1_OFF + wv * (QN * 64);
        {
            float* ab = attn + (size_t)b * QN * KTOT + krow0 + tid;
            #pragma unroll
            for (int q = 0; q < QN; ++q) {
                const float a = s[q] * inv;
                __builtin_nontemporal_store(a, ab + (size_t)q * KTOT);  // write-once stream
                smem[AW + q * 64 + lane] = a;                           // wave-private
                nacc[q] += a;
            }
        }

        // next tile's quarter 0 -> R0: all waves are past the qt3 barrier, so all
        // R0 readers (qt2) are done; rides through the whole barrier-free PV phase
        if (t + 1 < ntiles) { STAGE_QUARTER(R0_OFF, kb4 + TILE * 16, 0); }

        // ---- PV: U[q][lane=d] += a[q][k] * v[k][d]; wave owns 64 k-rows ----
        const float* vptr = value + ((size_t)b * KTOT + krow0 + wv * 64) * DN + lane;
        float va[8];
        #pragma unroll
        for (int i = 0; i < 8; ++i) va[i] = vptr[(size_t)i * DN];   // 256B/instr coalesced
        #pragma unroll 1
        for (int kk = 0; kk < 64; kk += 8) {
            float vb[8];
            const int nxt = kk + 8;
            if (nxt < 64) {
                #pragma unroll
                for (int i = 0; i < 8; ++i) vb[i] = vptr[(size_t)(nxt + i) * DN];
            }
            #pragma unroll
            for (int kq = 0; kq < 8; kq += 4) {
                #pragma unroll
                for (int q = 0; q < QN; ++q) {
                    const float4 av = *reinterpret_cast<const float4*>(
                        &smem[AW + q * 64 + kk + kq]);              // uniform broadcast
                    U[q] = fmaf(av.x, va[kq + 0], U[q]);
                    U[q] = fmaf(av.y, va[kq + 1], U[q]);
                    U[q] = fmaf(av.z, va[kq + 2], U[q]);
                    U[q] = fmaf(av.w, va[kq + 3], U[q]);
                }
            }
            #pragma unroll
            for (int i = 0; i < 8; ++i) va[i] = vb[i];
        }
    }

    // ---- block reductions: U across 4 waves (R0 region), nacc (R1 region) ----
    __syncthreads();
    #pragma unroll
    for (int q = 0; q < QN; ++q)
        smem[R0_OFF + (wv * QN + q) * DN + lane] = U[q];
    #pragma unroll
    for (int q = 0; q < QN; ++q) {
        #pragma unroll
        for (int off = 1; off < 64; off <<= 1)
            nacc[q] += __shfl_xor(nacc[q], off, 64);
    }
    if (lane == 0) {
        #pragma unroll
        for (int q = 0; q < QN; ++q) smem[R1_OFF + wv * QN + q] = nacc[q];
    }
    __syncthreads();

    {
        const int q = tid >> 4, d0 = (tid & 15) * 4;
        const float4 r0 = *reinterpret_cast<const float4*>(&smem[R0_OFF + (0 * QN + q) * DN + d0]);
        const float4 r1 = *reinterpret_cast<const float4*>(&smem[R0_OFF + (1 * QN + q) * DN + d0]);
        const float4 r2 = *reinterpret_cast<const float4*>(&smem[R0_OFF + (2 * QN + q) * DN + d0]);
        const float4 r3 = *reinterpret_cast<const float4*>(&smem[R0_OFF + (3 * QN + q) * DN + d0]);
        float4 rs;
        rs.x = r0.x + r1.x + r2.x + r3.x;
        rs.y = r0.y + r1.y + r2.y + r3.y;
        rs.z = r0.z + r1.z + r2.z + r3.z;
        rs.w = r0.w + r1.w + r2.w + r3.w;
        *reinterpret_cast<float4*>(
            &upart[(((size_t)b * NCH + c) * QN + q) * DN + d0]) = rs;
        if (tid < QN)
            normp[((size_t)b * NCH + c) * QN + tid] =
                smem[R1_OFF + tid] + smem[R1_OFF + QN + tid] +
                smem[R1_OFF + 2 * QN + tid] + smem[R1_OFF + 3 * QN + tid];
    }
}

// ---------------- Finalize: out[b][q][d] = sum_c U / (sum_c norm + eps); grid (8,16) --------
__global__ __launch_bounds__(256) void k3_fin(
    const float* __restrict__ upart, const float* __restrict__ normp,
    float* __restrict__ out, int NCH)
{
    const int b = blockIdx.x, q = blockIdx.y;
    const int tid = threadIdx.x;
    const int wv = tid >> 6, lane = tid & 63;

    float nv = 0.f;
    for (int c = tid; c < NCH; c += 256)
        nv += normp[((size_t)b * NCH + c) * QN + q];
    #pragma unroll
    for (int off = 1; off < 64; off <<= 1) nv += __shfl_xor(nv, off, 64);
    __shared__ float nred[4];
    if (lane == 0) nred[wv] = nv;

    float acc = 0.f;
    for (int c = wv; c < NCH; c += 4)
        acc += upart[(((size_t)b * NCH + c) * QN + q) * DN + lane];
    __shared__ float ured[4][DN];
    ured[wv][lane] = acc;
    __syncthreads();

    if (tid < DN) {
        const float n   = nred[0] + nred[1] + nred[2] + nred[3];
        const float inv = 1.0f / (n + 1e-8f);
        const float u   = ured[0][tid] + ured[1][tid] + ured[2][tid] + ured[3][tid];
        out[((size_t)b * QN + q) * DN + tid] = u * inv;
    }
}

extern "C" void kernel_launch(void* const* d_in, const int* in_sizes, int n_in,
                              void* d_out, int out_size, void* d_ws, size_t ws_size,
                              hipStream_t stream)
{
    const float* query = (const float*)d_in[0];
    const float* key   = (const float*)d_in[1];
    const float* value = (const float*)d_in[2];

    float* out  = (float*)d_out;                          // [8,16,64]
    float* attn = (float*)d_out + (size_t)BN * QN * DN;   // [8,1,16,65536]

    int NCH = 128;                                        // 1024 blocks
    while (NCH > 8 && (size_t)BN * NCH * QN * (DN + 1) * 4 > ws_size) NCH >>= 1;
    const int ntiles = (KTOT / NCH) / TILE;

    float* normp = (float*)d_ws;                          // [8][NCH][16]
    float* upart = (float*)d_ws + (size_t)BN * NCH * QN;  // [8][NCH][16][64]

    fused_attn<<<dim3(NCH, BN), 256, 0, stream>>>(query, key, value, attn,
                                                  normp, upart, NCH, ntiles);
    k3_fin   <<<dim3(BN, QN), 256, 0, stream>>>(upart, normp, out, NCH);
}

// Round 9
// 84.050 us; speedup vs baseline: 14.0753x; 1.7959x over previous
//
#include <hip/hip_runtime.h>

#define KTOT 65536
#define QN 16
#define DN 64
#define BN 8
#define TILE 256

// smem layout (floats) — 9216 floats = 36,864 B
#define QS_OFF 0                    // Q scaled: [16][64]                 = 1024 floats
#define R0_OFF 1024                 // K quarter region 0: [256][16]      = 4096
#define R1_OFF 5120                 // K quarter region 1: [256][16]      = 4096
                                    // R1 doubles as A: per-wave [16][64] slices (wave-private)
#define SMEM_FLOATS 9216

// async global->LDS, 16B per lane; dest = wave-uniform base + lane*16
__device__ __forceinline__ void gload_lds16(const float* g, float* l)
{
    __builtin_amdgcn_global_load_lds(
        (const __attribute__((address_space(1))) void*)g,
        (__attribute__((address_space(3))) void*)l, 16, 0, 0);
}

// Counted wait. "memory" clobber = compiler-level fence: no memory op (incl. gload_lds
// intrinsics / V loads / attn stores) crosses it, so the vmcnt ledger is exact.
// sched_barrier(0) stops reg-only ops hoisting past it (rule #18).
#define WAIT_VM(N)  do { asm volatile("s_waitcnt vmcnt(" #N ")" ::: "memory");      \
                         __builtin_amdgcn_sched_barrier(0); } while (0)
#define LGKM0()     do { asm volatile("s_waitcnt lgkmcnt(0)" ::: "memory");         \
                         __builtin_amdgcn_sched_barrier(0); } while (0)

// WAVE-PRIVATE staging (verified correct in round 7): wave wv stages ITS OWN rows
// 64wv..64wv+63 of one K quarter (16 float cols; qo4 = quarter*4 in float4 units).
// Each wave issues exactly 4 gload_lds -> its vmcnt tracks its own quarter.
// Source pre-swizzled: global col = (lane&3) ^ ((row>>1)&3); read applies same XOR.
#define STAGE_WV(RX, kb4, qo4)                                                      \
    {                                                                               \
        _Pragma("unroll")                                                           \
        for (int j = 0; j < 4; ++j) {                                               \
            const int r_ = (wv << 6) + (j << 4) + (lane >> 2);                      \
            const int p_ = (lane & 3) ^ ((r_ >> 1) & 3);                            \
            gload_lds16((const float*)((kb4) + r_ * 16 + (qo4) + p_),               \
                        (float*)(((float4*)&smem[RX]) + ((wv << 8) + (j << 6) + lane))); \
        }                                                                           \
    }

// dot quarter qt from region RX: thread owns row tid; Q broadcast from LDS (round-6 proven)
#define DOT_Q(qt, RX)                                                               \
    {                                                                               \
        _Pragma("unroll")                                                           \
        for (int cc = 0; cc < 4; ++cc) {                                            \
            const float4 kv = ((const float4*)&smem[RX])[tid * 4 + (cc ^ fr)];      \
            _Pragma("unroll")                                                       \
            for (int q = 0; q < QN; ++q) {                                          \
                const float4 qv = *reinterpret_cast<const float4*>(                 \
                    &smem[QS_OFF + q * DN + (qt) * 16 + cc * 4]);                   \
                s[q] = fmaf(kv.x, qv.x, s[q]);                                      \
                s[q] = fmaf(kv.y, qv.y, s[q]);                                      \
                s[q] = fmaf(kv.z, qv.z, s[q]);                                      \
                s[q] = fmaf(kv.w, qv.w, s[q]);                                      \
            }                                                                       \
        }                                                                           \
    }

// ------------- Fused: QK^T + softmax(Q) + attn write + PV partials + norm partials ----------
// ZERO barriers in the main loop. K staging wave-private (K rows have no cross-thread reuse),
// A wave-private (aliases own R1 slice), Q read-only after one prologue barrier. All waits
// are wave-local counted vmcnt -> waves free-run instead of lockstep vmcnt(0) draining
// (the invariant ~100us stall of rounds 3-6). Register budget = round 6's (~85), NOT
// round 7's 64-float V arrays (scratch catastrophe).
__global__ __launch_bounds__(256, 3) void fused_attn(
    const float* __restrict__ query, const float* __restrict__ key,
    const float* __restrict__ value, float* __restrict__ attn,
    float* __restrict__ normp, float* __restrict__ upart,
    int NCH, int ntiles)
{
    __shared__ float smem[SMEM_FLOATS];
    const int b    = blockIdx.y;
    const int c    = blockIdx.x;
    const int tid  = threadIdx.x;
    const int wv   = tid >> 6;
    const int lane = tid & 63;
    const int chunk = ntiles * TILE;
    const int fr   = (tid >> 1) & 3;
    const int AW   = R1_OFF + wv * (QN * 64);   // A: own 4KB slice of R1

    // Q -> LDS (scaled), ONE barrier; stages issued after it are never drained again
    {
        float4 qv = reinterpret_cast<const float4*>(query + (size_t)b * QN * DN)[tid];
        qv.x *= 0.125f; qv.y *= 0.125f; qv.z *= 0.125f; qv.w *= 0.125f;
        reinterpret_cast<float4*>(&smem[QS_OFF])[tid] = qv;
    }
    __syncthreads();

    {
        const float4* kb4 = reinterpret_cast<const float4*>(
            key + ((size_t)b * KTOT + c * chunk) * DN);
        STAGE_WV(R0_OFF, kb4, 0);   // tile0 q0
        STAGE_WV(R1_OFF, kb4, 4);   // tile0 q1
        __builtin_amdgcn_sched_barrier(0);
    }

    float U[QN], nacc[QN];
    #pragma unroll
    for (int q = 0; q < QN; ++q) { U[q] = 0.f; nacc[q] = 0.f; }

    for (int t = 0; t < ntiles; ++t) {
        const int krow0 = c * chunk + t * TILE;
        const float4* kb4  = reinterpret_cast<const float4*>(
            key + ((size_t)b * KTOT + krow0) * DN);
        const float4* kb4n = kb4 + TILE * 16;                         // next tile
        const float*  vptr = value + ((size_t)b * KTOT + krow0 + wv * 64) * DN + lane;

        float s[QN];
        #pragma unroll
        for (int q = 0; q < QN; ++q) s[q] = 0.f;

        // ledger (this wave's outstanding VM ops, oldest->youngest):
        // top of tile: [q0(4), q1(4)] (+fully-aged prev stores, older -> drained first)
        WAIT_VM(4);                                                   // q0 arrived
        DOT_Q(0, R0_OFF);
        LGKM0(); STAGE_WV(R0_OFF, kb4, 8);                            // q2 -> R0
        __builtin_amdgcn_sched_barrier(0);

        WAIT_VM(4);                                                   // q1 arrived: [q2]
        DOT_Q(1, R1_OFF);
        LGKM0(); STAGE_WV(R1_OFF, kb4, 12);                           // q3 -> R1
        __builtin_amdgcn_sched_barrier(0);

        WAIT_VM(4);                                                   // q2 arrived: [q3]
        DOT_Q(2, R0_OFF);

        // V batch 0 issued now (younger than q3) -> rides through dot q3 + softmax
        float va[8];
        #pragma unroll
        for (int i = 0; i < 8; ++i) va[i] = vptr[(size_t)i * DN];
        __builtin_amdgcn_sched_barrier(0);
        WAIT_VM(8);                                                   // q3 arrived: [va(8)]
        DOT_Q(3, R1_OFF);

        // ---- softmax over the 16 queries (thread-local, k = krow0 + tid) ----
        float m = s[0];
        #pragma unroll
        for (int q = 1; q < QN; ++q) m = fmaxf(m, s[q]);
        float sum = 0.f;
        #pragma unroll
        for (int q = 0; q < QN; ++q) { s[q] = __expf(s[q] - m); sum += s[q]; }
        const float inv = 1.0f / sum;
        {
            float* ab = attn + (size_t)b * QN * KTOT + krow0 + tid;
            #pragma unroll
            for (int q = 0; q < QN; ++q) {
                const float a = s[q] * inv;
                __builtin_nontemporal_store(a, ab + (size_t)q * KTOT);
                smem[AW + q * 64 + lane] = a;        // own slice; dot-q3 reads already retired
                nacc[q] += a;
            }
        }

        // ---- PV: U[q][lane=d] += a[q][k] * v[k][d]; wave owns 64 k-rows ----
        #pragma unroll 1
        for (int kk = 0; kk < 64; kk += 8) {
            float vb[8];
            const int nxt = kk + 8;
            if (nxt < 64) {
                #pragma unroll
                for (int i = 0; i < 8; ++i) vb[i] = vptr[(size_t)(nxt + i) * DN];
            }
            #pragma unroll
            for (int kq = 0; kq < 8; kq += 4) {
                #pragma unroll
                for (int q = 0; q < QN; ++q) {
                    const float4 av = *reinterpret_cast<const float4*>(
                        &smem[AW + q * 64 + kk + kq]);              // uniform broadcast
                    U[q] = fmaf(av.x, va[kq + 0], U[q]);
                    U[q] = fmaf(av.y, va[kq + 1], U[q]);
                    U[q] = fmaf(av.z, va[kq + 2], U[q]);
                    U[q] = fmaf(av.w, va[kq + 3], U[q]);
                }
            }
            #pragma unroll
            for (int i = 0; i < 8; ++i) va[i] = vb[i];
        }

        // next tile's q0,q1 issued at PV end: all this wave's R0/R1 reads are retired
        // (A reads consumed by U fmas; K reads consumed by s). Rides into next tile.
        if (t + 1 < ntiles) {
            LGKM0();
            STAGE_WV(R0_OFF, kb4n, 0);
            STAGE_WV(R1_OFF, kb4n, 4);
            __builtin_amdgcn_sched_barrier(0);
        }
    }

    // ---- block reductions: U across 4 waves (R0 region), nacc (R1 region) ----
    __syncthreads();                                   // full drain (outside main loop)
    #pragma unroll
    for (int q = 0; q < QN; ++q)
        smem[R0_OFF + (wv * QN + q) * DN + lane] = U[q];
    #pragma unroll
    for (int q = 0; q < QN; ++q) {
        #pragma unroll
        for (int off = 1; off < 64; off <<= 1)
            nacc[q] += __shfl_xor(nacc[q], off, 64);
    }
    if (lane == 0) {
        #pragma unroll
        for (int q = 0; q < QN; ++q) smem[R1_OFF + wv * QN + q] = nacc[q];
    }
    __syncthreads();

    {
        const int q = tid >> 4, d0 = (tid & 15) * 4;
        const float4 r0 = *reinterpret_cast<const float4*>(&smem[R0_OFF + (0 * QN + q) * DN + d0]);
        const float4 r1 = *reinterpret_cast<const float4*>(&smem[R0_OFF + (1 * QN + q) * DN + d0]);
        const float4 r2 = *reinterpret_cast<const float4*>(&smem[R0_OFF + (2 * QN + q) * DN + d0]);
        const float4 r3 = *reinterpret_cast<const float4*>(&smem[R0_OFF + (3 * QN + q) * DN + d0]);
        float4 rs;
        rs.x = r0.x + r1.x + r2.x + r3.x;
        rs.y = r0.y + r1.y + r2.y + r3.y;
        rs.z = r0.z + r1.z + r2.z + r3.z;
        rs.w = r0.w + r1.w + r2.w + r3.w;
        *reinterpret_cast<float4*>(
            &upart[(((size_t)b * NCH + c) * QN + q) * DN + d0]) = rs;
        if (tid < QN)
            normp[((size_t)b * NCH + c) * QN + tid] =
                smem[R1_OFF + tid] + smem[R1_OFF + QN + tid] +
                smem[R1_OFF + 2 * QN + tid] + smem[R1_OFF + 3 * QN + tid];
    }
}

// ------------- Finalize: out[b][q][d] = sum_c U / (sum_c norm + eps); grid (8,16) -----------
__global__ __launch_bounds__(256) void k3_fin(
    const float* __restrict__ upart, const float* __restrict__ normp,
    float* __restrict__ out, int NCH)
{
    const int b = blockIdx.x, q = blockIdx.y;
    const int tid = threadIdx.x;
    const int wv = tid >> 6, lane = tid & 63;

    float nv = 0.f;
    for (int c = tid; c < NCH; c += 256)
        nv += normp[((size_t)b * NCH + c) * QN + q];
    #pragma unroll
    for (int off = 1; off < 64; off <<= 1) nv += __shfl_xor(nv, off, 64);
    __shared__ float nred[4];
    if (lane == 0) nred[wv] = nv;

    float acc = 0.f;
    for (int c = wv; c < NCH; c += 4)
        acc += upart[(((size_t)b * NCH + c) * QN + q) * DN + lane];
    __shared__ float ured[4][DN];
    ured[wv][lane] = acc;
    __syncthreads();

    if (tid < DN) {
        const float n   = nred[0] + nred[1] + nred[2] + nred[3];
        const float inv = 1.0f / (n + 1e-8f);
        const float u   = ured[0][tid] + ured[1][tid] + ured[2][tid] + ured[3][tid];
        out[((size_t)b * QN + q) * DN + tid] = u * inv;
    }
}

extern "C" void kernel_launch(void* const* d_in, const int* in_sizes, int n_in,
                              void* d_out, int out_size, void* d_ws, size_t ws_size,
                              hipStream_t stream)
{
    const float* query = (const float*)d_in[0];
    const float* key   = (const float*)d_in[1];
    const float* value = (const float*)d_in[2];

    float* out  = (float*)d_out;                          // [8,16,64]
    float* attn = (float*)d_out + (size_t)BN * QN * DN;   // [8,1,16,65536]

    int NCH = 128;                                        // 1024 blocks
    while (NCH > 8 && (size_t)BN * NCH * QN * (DN + 1) * 4 > ws_size) NCH >>= 1;
    const int ntiles = (KTOT / NCH) / TILE;

    float* normp = (float*)d_ws;                          // [8][NCH][16]
    float* upart = (float*)d_ws + (size_t)BN * NCH * QN;  // [8][NCH][16][64]

    fused_attn<<<dim3(NCH, BN), 256, 0, stream>>>(query, key, value, attn,
                                                  normp, upart, NCH, ntiles);
    k3_fin   <<<dim3(BN, QN), 256, 0, stream>>>(upart, normp, out, NCH);
}